// Round 12
// baseline (179.659 us; speedup 1.0000x reference)
//
#include <hip/hip_runtime.h>

namespace {

constexpr int kN = 100;   // subactors
constexpr int kH = 16;    // hidden
constexpr int kS = 6;     // state
constexpr int kB = 128;   // batch
constexpr int kT = 128;   // time
constexpr int kNS = kN * kS;   // 600 floats per (b,t) row
constexpr int kXB = kT * kNS;  // 76800 floats per b
constexpr float kL2E = 1.44269504088896340736f;  // log2(e)

typedef float f32x4 __attribute__((ext_vector_type(4)));
typedef float vf2 __attribute__((ext_vector_type(2)));
typedef short bf16x8 __attribute__((ext_vector_type(8)));

union Frag {
  unsigned u[4];
  bf16x8 v;
};

// Manual RNE pack (proven; r10 showed v_cvt_pk_bf16_f32 breaks numerics).
__device__ __forceinline__ unsigned pkbf(float a, float b) {
  unsigned ua = __builtin_bit_cast(unsigned, a);
  unsigned ub = __builtin_bit_cast(unsigned, b);
  ua += 0x7fffu + ((ua >> 16) & 1u);
  ub += 0x7fffu + ((ub >> 16) & 1u);
  return (ua >> 16) | (ub & 0xffff0000u);
}

__device__ __forceinline__ float rcp_fast(float v) {
  return __builtin_amdgcn_rcpf(v);
}
__device__ __forceinline__ float exp2_fast(float v) {
  return __builtin_amdgcn_exp2f(v);
}
__device__ __forceinline__ vf2 pkfma(vf2 a, vf2 b, vf2 c) {
  return __builtin_elementwise_fma(a, b, c);
}

__device__ __forceinline__ f32x4 mfma16(bf16x8 a, bf16x8 b, f32x4 c) {
  return __builtin_amdgcn_mfma_f32_16x16x32_bf16(a, b, c, 0, 0, 0);
}

// K-slot permutation for lane-local B:
//   quad q supplies k-slots [8q..8q+3] = h rows 4q..4q+3,
//   [8q+4,8q+5] = x comps 2q,2q+1 (q<3), rest 0.
__device__ __forceinline__ void mkA(Frag& F, int qt, const float* hrow,
                                    const float* xrow, float sc) {
  F.u[0] = F.u[1] = F.u[2] = F.u[3] = 0u;
  if (hrow) {
    F.u[0] = pkbf(hrow[4 * qt + 0] * sc, hrow[4 * qt + 1] * sc);
    F.u[1] = pkbf(hrow[4 * qt + 2] * sc, hrow[4 * qt + 3] * sc);
  }
  if (xrow && qt < 3) {
    F.u[2] = pkbf(xrow[2 * qt + 0] * sc, xrow[2 * qt + 1] * sc);
  }
}

}  // namespace

// Wave = (n-pair {p, p+50}, 16-batch tile): 400 waves, TWO independent
// DS-free chains per wave. MFMAs of both chains are issued back-to-back so
// each chain's epilogue executes in the other's MFMA shadow — within-wave
// ILP replacing the TLP we can't get at 800 waves. Numerics = r11 exactly.
__global__ __launch_bounds__(64) void actor_dual(
    const float* __restrict__ x, const float* __restrict__ Wih,
    const float* __restrict__ Whh, const float* __restrict__ bih,
    const float* __restrict__ bhh, const float* __restrict__ W1,
    const float* __restrict__ b1, const float* __restrict__ W2,
    const float* __restrict__ b2, const float* __restrict__ W3,
    const float* __restrict__ b3, float* __restrict__ out) {
  const int tid = (int)threadIdx.x;
  const int j = tid & 15;
  const int qt = tid >> 4;
  const int np = (int)blockIdx.x >> 3;  // 0..49
  const int bt = (int)blockIdx.x & 7;

  // ---- per-chain constants ----
  Frag Ar[2], Az[2], Anh[2], Anx[2], Ay1[2], Ay2[2];
  f32x4 Cbr[2], Cbz[2], Cbhn[2], Cbin[2], Cb1[2], Cb2[2];
  vf2 w301[2], w323[2];
  float b3s[2];
  const float* px[2];
  float* outp[2];

#pragma unroll
  for (int c = 0; c < 2; ++c) {
    const int n = np + 50 * c;
    mkA(Ar[c], qt, Whh + ((size_t)n * 48 + j) * 16,
        Wih + ((size_t)n * 48 + j) * 6, kL2E);
    mkA(Az[c], qt, Whh + ((size_t)n * 48 + 16 + j) * 16,
        Wih + ((size_t)n * 48 + 16 + j) * 6, kL2E);
    mkA(Anh[c], qt, Whh + ((size_t)n * 48 + 32 + j) * 16, nullptr,
        2.0f * kL2E);
    mkA(Anx[c], qt, nullptr, Wih + ((size_t)n * 48 + 32 + j) * 6,
        2.0f * kL2E);
    mkA(Ay1[c], qt, W1 + ((size_t)n * 16 + j) * 16, nullptr, 1.0f);
    mkA(Ay2[c], qt, W2 + ((size_t)n * 16 + j) * 16, nullptr, 1.0f);
#pragma unroll
    for (int r = 0; r < 4; ++r) {
      const int gi = n * 48 + 4 * qt + r;
      Cbr[c][r] = (bih[gi] + bhh[gi]) * kL2E;
      Cbz[c][r] = (bih[gi + 16] + bhh[gi + 16]) * kL2E;
      Cbin[c][r] = bih[gi + 32] * 2.0f * kL2E;
      Cbhn[c][r] = bhh[gi + 32] * 2.0f * kL2E;
      const int hi = n * 16 + 4 * qt + r;
      Cb1[c][r] = b1[hi];
      Cb2[c][r] = b2[hi];
    }
    w301[c] = (vf2){W3[n * 16 + 4 * qt + 0], W3[n * 16 + 4 * qt + 1]};
    w323[c] = (vf2){W3[n * 16 + 4 * qt + 2], W3[n * 16 + 4 * qt + 3]};
    b3s[c] = b3[n];
    const int b = bt * 16 + j;
    px[c] = x + (size_t)b * kXB + (size_t)n * kS + (qt < 3 ? 2 * qt : 0);
    outp[c] = out + ((size_t)n * kB + b) * kT;
  }

  // ---- per-chain state ----
  float2 xr[2][4];
#pragma unroll
  for (int c = 0; c < 2; ++c)
#pragma unroll
    for (int i = 0; i < 4; ++i)
      xr[c][i] = *(const float2*)(px[c] + (size_t)i * kNS);

  vf2 hp01[2] = {(vf2){0.f, 0.f}, (vf2){0.f, 0.f}};
  vf2 hp23[2] = {(vf2){0.f, 0.f}, (vf2){0.f, 0.f}};
  unsigned P0[2] = {0u, 0u}, P1[2] = {0u, 0u};

  const f32x4 zero4 = {0.f, 0.f, 0.f, 0.f};
  f32x4 Cy1p[2] = {zero4, zero4};
  f32x4 Cy2p[2] = {zero4, zero4};
  float s4[2][4] = {{0.f, 0.f, 0.f, 0.f}, {0.f, 0.f, 0.f, 0.f}};

  const vf2 one2 = (vf2){1.f, 1.f};
  const vf2 m2 = (vf2){-2.f, -2.f};
  const vf2 z2 = (vf2){0.f, 0.f};

  auto step = [&](int t, bool doRec, bool doA, bool doB, bool doC) {
    f32x4 Cr[2], Cz[2], Chn[2], Cxn[2], Cy1n[2];
    Cy1n[0] = Cy1p[0];
    Cy1n[1] = Cy1p[1];

    // ---- phase 1: issue ALL MFMAs of both chains back-to-back ----
    if (t <= kT) {
      const int sl = t & 3;
#pragma unroll
      for (int c = 0; c < 2; ++c) {
        Frag Bf;
        Bf.u[0] = P0[c];
        Bf.u[1] = P1[c];
        Bf.u[2] = (qt < 3) ? pkbf(xr[c][sl].x, xr[c][sl].y) : 0u;
        Bf.u[3] = 0u;
        {
          int tc = t + 4;
          if (tc > kT - 1) tc = kT - 1;
          xr[c][sl] = *(const float2*)(px[c] + (size_t)tc * kNS);
        }
        if (doRec) {
          Cr[c] = mfma16(Ar[c].v, Bf.v, Cbr[c]);
          Cz[c] = mfma16(Az[c].v, Bf.v, Cbz[c]);
          Chn[c] = mfma16(Anh[c].v, Bf.v, Cbhn[c]);
          Cxn[c] = mfma16(Anx[c].v, Bf.v, Cbin[c]);
        }
        Cy1n[c] = mfma16(Ay1[c].v, Bf.v, Cb1[c]);
      }
    }

    // ---- phase 2: y stages (consume previous-step results; fill shadow) ----
#pragma unroll
    for (int c = 0; c < 2; ++c) {
      if (doB) {
        vf2 a = __builtin_elementwise_max((vf2){Cy2p[c][0], Cy2p[c][1]}, z2);
        vf2 d = __builtin_elementwise_max((vf2){Cy2p[c][2], Cy2p[c][3]}, z2);
        vf2 p = pkfma(d, w323[c], a * w301[c]);
        s4[c][(t - 3) & 3] = p.x + p.y;
      }
      if (doA) {
        vf2 a = __builtin_elementwise_max((vf2){Cy1p[c][0], Cy1p[c][1]}, z2);
        vf2 d = __builtin_elementwise_max((vf2){Cy1p[c][2], Cy1p[c][3]}, z2);
        Frag By;
        By.u[0] = pkbf(a.x, a.y);
        By.u[1] = pkbf(d.x, d.y);
        By.u[2] = 0u;
        By.u[3] = 0u;
        Cy2p[c] = mfma16(Ay2[c].v, By.v, Cb2[c]);
      }
    }

    if (doC) {
#pragma unroll
      for (int c = 0; c < 2; ++c) {
        float v0 = s4[c][0], v1 = s4[c][1], v2 = s4[c][2], v3 = s4[c][3];
        v0 += __shfl_xor(v0, 16);
        v1 += __shfl_xor(v1, 16);
        v2 += __shfl_xor(v2, 16);
        v3 += __shfl_xor(v3, 16);
        v0 += __shfl_xor(v0, 32);
        v1 += __shfl_xor(v1, 32);
        v2 += __shfl_xor(v2, 32);
        v3 += __shfl_xor(v3, 32);
        if (qt == 0) {
          float4 o = {fmaxf(v0 + b3s[c], 0.f), fmaxf(v1 + b3s[c], 0.f),
                      fmaxf(v2 + b3s[c], 0.f), fmaxf(v3 + b3s[c], 0.f)};
          *(float4*)(outp[c] + (t - 6)) = o;
        }
      }
    }

    // ---- phase 3: gate epilogues (chain c=0 runs in c=1's MFMA shadow) ----
    if (doRec) {
#pragma unroll
      for (int c = 0; c < 2; ++c) {
        vf2 cr01 = {Cr[c][0], Cr[c][1]}, cr23 = {Cr[c][2], Cr[c][3]};
        vf2 cz01 = {Cz[c][0], Cz[c][1]}, cz23 = {Cz[c][2], Cz[c][3]};
        vf2 chn01 = {Chn[c][0], Chn[c][1]}, chn23 = {Chn[c][2], Chn[c][3]};
        vf2 cxn01 = {Cxn[c][0], Cxn[c][1]}, cxn23 = {Cxn[c][2], Cxn[c][3]};

        vf2 er01 = {exp2_fast(-cr01.x), exp2_fast(-cr01.y)};
        vf2 er23 = {exp2_fast(-cr23.x), exp2_fast(-cr23.y)};
        vf2 dr01 = er01 + one2, dr23 = er23 + one2;
        vf2 rr01 = {rcp_fast(dr01.x), rcp_fast(dr01.y)};
        vf2 rr23 = {rcp_fast(dr23.x), rcp_fast(dr23.y)};

        vf2 ez01 = {exp2_fast(-cz01.x), exp2_fast(-cz01.y)};
        vf2 ez23 = {exp2_fast(-cz23.x), exp2_fast(-cz23.y)};
        vf2 dz01 = ez01 + one2, dz23 = ez23 + one2;
        vf2 zz01 = {rcp_fast(dz01.x), rcp_fast(dz01.y)};
        vf2 zz23 = {rcp_fast(dz23.x), rcp_fast(dz23.y)};

        vf2 np01 = pkfma(rr01, chn01, cxn01);
        vf2 np23 = pkfma(rr23, chn23, cxn23);
        vf2 en01 = {exp2_fast(np01.x), exp2_fast(np01.y)};
        vf2 en23 = {exp2_fast(np23.x), exp2_fast(np23.y)};
        vf2 dn01 = en01 + one2, dn23 = en23 + one2;
        vf2 rn01 = {rcp_fast(dn01.x), rcp_fast(dn01.y)};
        vf2 rn23 = {rcp_fast(dn23.x), rcp_fast(dn23.y)};
        vf2 nn01 = pkfma(m2, rn01, one2);
        vf2 nn23 = pkfma(m2, rn23, one2);

        hp01[c] = pkfma(zz01, hp01[c] - nn01, nn01);
        hp23[c] = pkfma(zz23, hp23[c] - nn23, nn23);
        P0[c] = pkbf(hp01[c].x, hp01[c].y);
        P1[c] = pkbf(hp23[c].x, hp23[c].y);
      }
    }

    Cy1p[0] = Cy1n[0];
    Cy1p[1] = Cy1n[1];
  };

  // peel: fill the y pipeline
  step(0, true, false, false, false);
  step(1, true, false, false, false);
  step(2, true, true, false, false);
  step(3, true, true, true, false);

  for (int t4 = 4; t4 < kT; t4 += 4) {
    step(t4 + 0, true, true, true, false);
    step(t4 + 1, true, true, true, false);
    step(t4 + 2, true, true, true, true);  // reduce+store every 4 steps
    step(t4 + 3, true, true, true, false);
  }

  // drain
  step(kT, false, true, true, false);
  step(kT + 1, false, true, true, false);
  step(kT + 2, false, false, true, true);  // stores times 124..127
}

extern "C" void kernel_launch(void* const* d_in, const int* in_sizes, int n_in,
                              void* d_out, int out_size, void* d_ws,
                              size_t ws_size, hipStream_t stream) {
  const float* x = (const float*)d_in[0];
  const float* Wih = (const float*)d_in[1];
  const float* Whh = (const float*)d_in[2];
  const float* bih = (const float*)d_in[3];
  const float* bhh = (const float*)d_in[4];
  const float* W1 = (const float*)d_in[5];
  const float* b1 = (const float*)d_in[6];
  const float* W2 = (const float*)d_in[7];
  const float* b2 = (const float*)d_in[8];
  const float* W3 = (const float*)d_in[9];
  const float* b3 = (const float*)d_in[10];
  float* out = (float*)d_out;

  actor_dual<<<dim3(50 * 8), dim3(64), 0, stream>>>(x, Wih, Whh, bih, bhh, W1,
                                                    b1, W2, b2, W3, b3, out);
}

// Round 13
// 133.665 us; speedup vs baseline: 1.3441x; 1.3441x over previous
//
#include <hip/hip_runtime.h>

namespace {

constexpr int kN = 100;   // subactors
constexpr int kH = 16;    // hidden
constexpr int kS = 6;     // state
constexpr int kB = 128;   // batch
constexpr int kT = 128;   // time
constexpr int kNS = kN * kS;   // 600 floats per (b,t) row
constexpr int kXB = kT * kNS;  // 76800 floats per b
constexpr float kL2E = 1.44269504088896340736f;  // log2(e)

typedef float f32x4 __attribute__((ext_vector_type(4)));
typedef float vf2 __attribute__((ext_vector_type(2)));
typedef short bf16x8 __attribute__((ext_vector_type(8)));

union Frag {
  unsigned u[4];
  bf16x8 v;
};

// Manual RNE pack (proven; r10 showed v_cvt_pk_bf16_f32 breaks numerics).
__device__ __forceinline__ unsigned pkbf(float a, float b) {
  unsigned ua = __builtin_bit_cast(unsigned, a);
  unsigned ub = __builtin_bit_cast(unsigned, b);
  ua += 0x7fffu + ((ua >> 16) & 1u);
  ub += 0x7fffu + ((ub >> 16) & 1u);
  return (ua >> 16) | (ub & 0xffff0000u);
}

__device__ __forceinline__ float rcp_fast(float v) {
  return __builtin_amdgcn_rcpf(v);
}
__device__ __forceinline__ float exp2_fast(float v) {
  return __builtin_amdgcn_exp2f(v);
}
__device__ __forceinline__ vf2 pkfma(vf2 a, vf2 b, vf2 c) {
  return __builtin_elementwise_fma(a, b, c);
}

__device__ __forceinline__ f32x4 mfma16(bf16x8 a, bf16x8 b, f32x4 c) {
  return __builtin_amdgcn_mfma_f32_16x16x32_bf16(a, b, c, 0, 0, 0);
}

// K-slot permutation for lane-local B:
//   quad q supplies k-slots [8q..8q+3] = h rows 4q..4q+3,
//   [8q+4,8q+5] = x comps 2q,2q+1 (q<3), rest 0.
__device__ __forceinline__ void mkA(Frag& F, int qt, const float* hrow,
                                    const float* xrow, float sc) {
  F.u[0] = F.u[1] = F.u[2] = F.u[3] = 0u;
  if (hrow) {
    F.u[0] = pkbf(hrow[4 * qt + 0] * sc, hrow[4 * qt + 1] * sc);
    F.u[1] = pkbf(hrow[4 * qt + 2] * sc, hrow[4 * qt + 3] * sc);
  }
  if (xrow && qt < 3) {
    F.u[2] = pkbf(xrow[2 * qt + 0] * sc, xrow[2 * qt + 1] * sc);
  }
}

}  // namespace

// r11 structure (wave = (n, 16-batch tile), 800 waves, lane-local B, y-path
// pipelined 2 deep, packed epilogue, bias-in-C, exp2-native) with body-level
// x double-buffering: two 4-deep ping-pong register buffers, loads issued in
// groups of 4 and consumed 4-8 steps later, so any conservative s_waitcnt
// drains long-retired loads at most once per 4 steps (r13 theory: the
// per-step vmcnt drain was the ~400cy/step hidden stall).
__global__ __launch_bounds__(64) void actor_db(
    const float* __restrict__ x, const float* __restrict__ Wih,
    const float* __restrict__ Whh, const float* __restrict__ bih,
    const float* __restrict__ bhh, const float* __restrict__ W1,
    const float* __restrict__ b1, const float* __restrict__ W2,
    const float* __restrict__ b2, const float* __restrict__ W3,
    const float* __restrict__ b3, float* __restrict__ out) {
  const int tid = (int)threadIdx.x;
  const int j = tid & 15;
  const int qt = tid >> 4;
  const int n = (int)blockIdx.x >> 3;
  const int bt = (int)blockIdx.x & 7;

  // ---- A fragments, K-permuted, log2e-prescaled ----
  Frag Ar, Az, Anh, Anx, Ay1, Ay2;
  mkA(Ar, qt, Whh + ((size_t)n * 48 + j) * 16, Wih + ((size_t)n * 48 + j) * 6,
      kL2E);
  mkA(Az, qt, Whh + ((size_t)n * 48 + 16 + j) * 16,
      Wih + ((size_t)n * 48 + 16 + j) * 6, kL2E);
  mkA(Anh, qt, Whh + ((size_t)n * 48 + 32 + j) * 16, nullptr, 2.0f * kL2E);
  mkA(Anx, qt, nullptr, Wih + ((size_t)n * 48 + 32 + j) * 6, 2.0f * kL2E);
  mkA(Ay1, qt, W1 + ((size_t)n * 16 + j) * 16, nullptr, 1.0f);
  mkA(Ay2, qt, W2 + ((size_t)n * 16 + j) * 16, nullptr, 1.0f);

  // ---- biases as MFMA C operands ----
  f32x4 Cbr, Cbz, Cbhn, Cbin, Cb1, Cb2;
  vf2 w301, w323;
#pragma unroll
  for (int r = 0; r < 4; ++r) {
    const int gi = n * 48 + 4 * qt + r;
    Cbr[r] = (bih[gi] + bhh[gi]) * kL2E;
    Cbz[r] = (bih[gi + 16] + bhh[gi + 16]) * kL2E;
    Cbin[r] = bih[gi + 32] * 2.0f * kL2E;
    Cbhn[r] = bhh[gi + 32] * 2.0f * kL2E;
    const int hi = n * 16 + 4 * qt + r;
    Cb1[r] = b1[hi];
    Cb2[r] = b2[hi];
  }
  w301 = (vf2){W3[n * 16 + 4 * qt + 0], W3[n * 16 + 4 * qt + 1]};
  w323 = (vf2){W3[n * 16 + 4 * qt + 2], W3[n * 16 + 4 * qt + 3]};
  const float b3s = b3[n];

  const int b = bt * 16 + j;
  // quad 3 packs x0,x1 too (harmless: its A x-slots are zero, x is finite)
  const float* px =
      x + (size_t)b * kXB + (size_t)n * kS + (qt < 3 ? 2 * qt : 0);
  float* outp = out + ((size_t)n * kB + b) * kT;

  // ---- x ping-pong: xa = steps t8..t8+3, xb = t8+4..t8+7 ----
  float2 xa[4], xb[4];
#pragma unroll
  for (int i = 0; i < 4; ++i) {
    xa[i] = *(const float2*)(px + (size_t)i * kNS);
    xb[i] = *(const float2*)(px + (size_t)(i + 4) * kNS);
  }

  vf2 hp01 = (vf2){0.f, 0.f}, hp23 = (vf2){0.f, 0.f};
  unsigned P0 = 0u, P1 = 0u;

  const f32x4 zero4 = {0.f, 0.f, 0.f, 0.f};
  f32x4 Cy1p = zero4;  // Cy1 issued previous step (time t-2 at step t)
  f32x4 Cy2p = zero4;  // Cy2 issued previous step (time t-3 at step t)
  float s4[4] = {0.f, 0.f, 0.f, 0.f};

  const vf2 one2 = (vf2){1.f, 1.f};
  const vf2 m2 = (vf2){-2.f, -2.f};
  const vf2 z2 = (vf2){0.f, 0.f};

  // One pipeline step consuming pre-loaded x (xv). Stages as in r11.
  auto step = [&](int t, float2 xv, bool doRec, bool doA, bool doB,
                  bool doC) {
    f32x4 Cr, Cz, Chn, Cxn, Cy1n = Cy1p;
    if (t <= kT) {
      Frag Bf;
      Bf.u[0] = P0;
      Bf.u[1] = P1;
      Bf.u[2] = pkbf(xv.x, xv.y);
      Bf.u[3] = 0u;
      if (doRec) {
        Cr = mfma16(Ar.v, Bf.v, Cbr);
        Cz = mfma16(Az.v, Bf.v, Cbz);
        Chn = mfma16(Anh.v, Bf.v, Cbhn);
        Cxn = mfma16(Anx.v, Bf.v, Cbin);
      }
      Cy1n = mfma16(Ay1.v, Bf.v, Cb1);  // y1 pre-act for time t-1
    }

    // stage B: packed partial s for time t-3 from Cy2p
    if (doB) {
      vf2 a = __builtin_elementwise_max((vf2){Cy2p[0], Cy2p[1]}, z2);
      vf2 c = __builtin_elementwise_max((vf2){Cy2p[2], Cy2p[3]}, z2);
      vf2 p = pkfma(c, w323, a * w301);
      s4[(t - 3) & 3] = p.x + p.y;
    }

    // stage A: packed relu + RNE pack of y1(time t-2), issue Cy2
    if (doA) {
      vf2 a = __builtin_elementwise_max((vf2){Cy1p[0], Cy1p[1]}, z2);
      vf2 c = __builtin_elementwise_max((vf2){Cy1p[2], Cy1p[3]}, z2);
      Frag By;
      By.u[0] = pkbf(a.x, a.y);
      By.u[1] = pkbf(c.x, c.y);
      By.u[2] = 0u;
      By.u[3] = 0u;
      Cy2p = mfma16(Ay2.v, By.v, Cb2);
    }

    // stage C: batched 16-lane reduce + float4 store of times t-6..t-3
    if (doC) {
      float v0 = s4[0], v1 = s4[1], v2 = s4[2], v3 = s4[3];
      v0 += __shfl_xor(v0, 16);
      v1 += __shfl_xor(v1, 16);
      v2 += __shfl_xor(v2, 16);
      v3 += __shfl_xor(v3, 16);
      v0 += __shfl_xor(v0, 32);
      v1 += __shfl_xor(v1, 32);
      v2 += __shfl_xor(v2, 32);
      v3 += __shfl_xor(v3, 32);
      if (qt == 0) {
        float4 o = {fmaxf(v0 + b3s, 0.f), fmaxf(v1 + b3s, 0.f),
                    fmaxf(v2 + b3s, 0.f), fmaxf(v3 + b3s, 0.f)};
        *(float4*)(outp + (t - 6)) = o;
      }
    }

    // packed gate epilogue -> h_t
    if (doRec) {
      vf2 cr01 = {Cr[0], Cr[1]}, cr23 = {Cr[2], Cr[3]};
      vf2 cz01 = {Cz[0], Cz[1]}, cz23 = {Cz[2], Cz[3]};
      vf2 chn01 = {Chn[0], Chn[1]}, chn23 = {Chn[2], Chn[3]};
      vf2 cxn01 = {Cxn[0], Cxn[1]}, cxn23 = {Cxn[2], Cxn[3]};

      vf2 er01 = {exp2_fast(-cr01.x), exp2_fast(-cr01.y)};
      vf2 er23 = {exp2_fast(-cr23.x), exp2_fast(-cr23.y)};
      vf2 dr01 = er01 + one2, dr23 = er23 + one2;
      vf2 rr01 = {rcp_fast(dr01.x), rcp_fast(dr01.y)};
      vf2 rr23 = {rcp_fast(dr23.x), rcp_fast(dr23.y)};

      vf2 ez01 = {exp2_fast(-cz01.x), exp2_fast(-cz01.y)};
      vf2 ez23 = {exp2_fast(-cz23.x), exp2_fast(-cz23.y)};
      vf2 dz01 = ez01 + one2, dz23 = ez23 + one2;
      vf2 zz01 = {rcp_fast(dz01.x), rcp_fast(dz01.y)};
      vf2 zz23 = {rcp_fast(dz23.x), rcp_fast(dz23.y)};

      vf2 np01 = pkfma(rr01, chn01, cxn01);
      vf2 np23 = pkfma(rr23, chn23, cxn23);
      vf2 en01 = {exp2_fast(np01.x), exp2_fast(np01.y)};
      vf2 en23 = {exp2_fast(np23.x), exp2_fast(np23.y)};
      vf2 dn01 = en01 + one2, dn23 = en23 + one2;
      vf2 rn01 = {rcp_fast(dn01.x), rcp_fast(dn01.y)};
      vf2 rn23 = {rcp_fast(dn23.x), rcp_fast(dn23.y)};
      vf2 nn01 = pkfma(m2, rn01, one2);
      vf2 nn23 = pkfma(m2, rn23, one2);

      hp01 = pkfma(zz01, hp01 - nn01, nn01);
      hp23 = pkfma(zz23, hp23 - nn23, nn23);
      P0 = pkbf(hp01.x, hp01.y);
      P1 = pkbf(hp23.x, hp23.y);
    }

    Cy1p = Cy1n;
  };

  // main loop: 8-step windows. First half consumes xa then refills xa with
  // t8+8..t8+11 (consumed next window, >=4 steps of slack); second half
  // likewise for xb.
  for (int t8 = 0; t8 < kT; t8 += 8) {
    const bool p0 = (t8 > 0);          // stages active after pipeline fill
    // steps t8+0 .. t8+3 (consume xa)
    step(t8 + 0, xa[0], true, p0 || false, p0, false);
    step(t8 + 1, xa[1], true, true, p0, false);
    step(t8 + 2, xa[2], true, true, true, p0);
    step(t8 + 3, xa[3], true, true, true, false);
    // refill xa with t8+8..t8+11 (clamped)
#pragma unroll
    for (int i = 0; i < 4; ++i) {
      int tc = t8 + 8 + i;
      if (tc > kT - 1) tc = kT - 1;
      xa[i] = *(const float2*)(px + (size_t)tc * kNS);
    }
    // steps t8+4 .. t8+7 (consume xb)
    step(t8 + 4, xb[0], true, true, true, false);
    step(t8 + 5, xb[1], true, true, true, false);
    step(t8 + 6, xb[2], true, true, true, true);
    step(t8 + 7, xb[3], true, true, true, false);
    // refill xb with t8+12..t8+15 (clamped)
#pragma unroll
    for (int i = 0; i < 4; ++i) {
      int tc = t8 + 12 + i;
      if (tc > kT - 1) tc = kT - 1;
      xb[i] = *(const float2*)(px + (size_t)tc * kNS);
    }
  }

  // drain (x no longer consumed)
  const float2 xz = {0.f, 0.f};
  step(kT, xz, false, true, true, false);
  step(kT + 1, xz, false, true, true, false);
  step(kT + 2, xz, false, false, true, true);  // stores times 124..127
}

extern "C" void kernel_launch(void* const* d_in, const int* in_sizes, int n_in,
                              void* d_out, int out_size, void* d_ws,
                              size_t ws_size, hipStream_t stream) {
  const float* x = (const float*)d_in[0];
  const float* Wih = (const float*)d_in[1];
  const float* Whh = (const float*)d_in[2];
  const float* bih = (const float*)d_in[3];
  const float* bhh = (const float*)d_in[4];
  const float* W1 = (const float*)d_in[5];
  const float* b1 = (const float*)d_in[6];
  const float* W2 = (const float*)d_in[7];
  const float* b2 = (const float*)d_in[8];
  const float* W3 = (const float*)d_in[9];
  const float* b3 = (const float*)d_in[10];
  float* out = (float*)d_out;

  actor_db<<<dim3(kN * 8), dim3(64), 0, stream>>>(x, Wih, Whh, bih, bhh, W1,
                                                  b1, W2, b2, W3, b3, out);
}